// Round 4
// baseline (2611.309 us; speedup 1.0000x reference)
//
#include <hip/hip_runtime.h>
#include <cstdint>

#define T_DIM 2048
#define B_DIM 16
#define D_DIM 1024
#define M_DIM (T_DIM * B_DIM)        // 32768 rows
#define BD (B_DIM * D_DIM)           // 16384 independent scan states
#define BD4 (BD / 4)                 // 4096 float4 columns
#define CCH 64                       // scan chunks
#define LCH (T_DIM / CCH)            // 32 steps per chunk

typedef _Float16 f16x8 __attribute__((ext_vector_type(8)));
typedef float f32x4 __attribute__((ext_vector_type(4)));

// async global -> LDS, 16B per lane. LDS dest must be wave-uniform base +
// lane*16 (tid*16 satisfies this per 64-lane wave). Dest is LINEAR; the
// bank-conflict swizzle is applied on the SOURCE address + the LDS READ
// (same XOR involution on both sides — guide rule #21).
__device__ __forceinline__ void async_cp16(const void* g, void* l) {
  __builtin_amdgcn_global_load_lds(
      (const __attribute__((address_space(1))) void*)(uintptr_t)g,
      (__attribute__((address_space(3))) void*)(uint32_t)(uintptr_t)l,
      16, 0, 0);
}

__device__ __forceinline__ float sigmoidf_(float z) {
  return 1.f / (1.f + __expf(-z));
}
__device__ __forceinline__ float tanhf_(float z) {
  float t = __expf(2.f * z);
  return (t - 1.f) / (t + 1.f);
}

// ---------------- f32 -> f16 convert, 8 elems/thread ----------------
__global__ void cvt_f32_f16(const float* __restrict__ s, _Float16* __restrict__ d, int n8) {
  int i = blockIdx.x * blockDim.x + threadIdx.x;
  if (i >= n8) return;
  const float4* sp = (const float4*)s;
  float4 u = sp[2 * i];
  float4 v = sp[2 * i + 1];
  f16x8 o;
  o[0] = (_Float16)u.x; o[1] = (_Float16)u.y; o[2] = (_Float16)u.z; o[3] = (_Float16)u.w;
  o[4] = (_Float16)v.x; o[5] = (_Float16)v.y; o[6] = (_Float16)v.z; o[7] = (_Float16)v.w;
  *(f16x8*)(d + (size_t)i * 8) = o;
}

// ---------------- fused 3-gate GEMM + gate combine ----------------
// Tile 128x128, BK=32, 8 waves (2x4), wave tile 64x32, mfma 16x16x32 f16.
// LDS rows are 64B (32 f16): 4 chunks of 16B. Swizzle: chunk' = chunk ^ ((row>>1)&3)
// -> per-16-lane read group spreads over all 8 bank-quads (2-way = free).
// ALL LDS is carved from one explicit smem block (no cross-array layout
// assumptions — that was round 3's UB: tb overflowed sA into assumed-adjacent sB).
__global__ __launch_bounds__(512, 2) void gate_gemm(
    const _Float16* __restrict__ x16,
    const _Float16* __restrict__ wa16,
    const _Float16* __restrict__ wk16,
    const _Float16* __restrict__ wv16,
    const float* __restrict__ ba, const float* __restrict__ bk, const float* __restrict__ bv,
    float* __restrict__ Aret, float* __restrict__ Bwr) {
  __shared__ __align__(16) char smem[65536];
  // [0, 16Ki)  : sA[2][128][32] f16
  // [16Ki,64Ki): sB[2][3][128][32] f16
  // epilogue   : tb = per-wave 32x33 f32 transpose buffers from offset 0 (33 KiB)
  auto sA = (_Float16 (*)[128][32])(smem);
  auto sB = (_Float16 (*)[3][128][32])(smem + 16384);

  const int tid  = threadIdx.x;
  const int wid  = tid >> 6;
  const int lane = tid & 63;
  const int wm = wid >> 2;    // 0..1 : 64-row slab
  const int wn = wid & 3;     // 0..3 : 32-col slab
  const int lr = lane & 15;
  const int kg = lane >> 4;

  const int m0 = blockIdx.x * 128;
  const int n0 = blockIdx.y * 128;

  const int arow = tid >> 2;                      // 0..127
  const int achk = tid & 3;                       // LDS slot this lane fills
  const int aswz = achk ^ ((arow >> 1) & 3);      // global chunk that belongs there

  f32x4 acc[3][4][2];
#pragma unroll
  for (int w = 0; w < 3; ++w)
#pragma unroll
    for (int mi = 0; mi < 4; ++mi)
#pragma unroll
      for (int ni = 0; ni < 2; ++ni)
        acc[w][mi][ni] = (f32x4)0.f;

  const size_t gA0 = (size_t)(m0 + arow) * D_DIM + aswz * 8;
  const size_t gB0 = (size_t)(n0 + arow) * D_DIM + aswz * 8;

  auto stage = [&](int buf, int kk) {
    async_cp16(x16  + gA0 + kk * 32, (char*)&sA[buf][0][0]    + tid * 16);
    async_cp16(wa16 + gB0 + kk * 32, (char*)&sB[buf][0][0][0] + tid * 16);
    async_cp16(wk16 + gB0 + kk * 32, (char*)&sB[buf][1][0][0] + tid * 16);
    async_cp16(wv16 + gB0 + kk * 32, (char*)&sB[buf][2][0][0] + tid * 16);
  };

  const int slot = (kg ^ ((lr >> 1) & 3)) * 8;    // swizzled 16B slot (8 f16)

  auto compute = [&](int buf) {
    f16x8 af[4];
#pragma unroll
    for (int mi = 0; mi < 4; ++mi)
      af[mi] = *(const f16x8*)&sA[buf][wm * 64 + mi * 16 + lr][slot];
#pragma unroll
    for (int w = 0; w < 3; ++w) {
      f16x8 b0 = *(const f16x8*)&sB[buf][w][wn * 32 + lr][slot];
      f16x8 b1 = *(const f16x8*)&sB[buf][w][wn * 32 + 16 + lr][slot];
#pragma unroll
      for (int mi = 0; mi < 4; ++mi) {
        acc[w][mi][0] = __builtin_amdgcn_mfma_f32_16x16x32_f16(af[mi], b0, acc[w][mi][0], 0, 0, 0);
        acc[w][mi][1] = __builtin_amdgcn_mfma_f32_16x16x32_f16(af[mi], b1, acc[w][mi][1], 0, 0, 0);
      }
    }
  };

  stage(0, 0);
  __syncthreads();
  int cur = 0;
#pragma unroll 1
  for (int kk = 0; kk < 32; ++kk) {
    if (kk + 1 < 32) stage(cur ^ 1, kk + 1);  // next-tile loads fly under MFMA
    compute(cur);
    __syncthreads();                           // drains vmcnt+lgkmcnt
    cur ^= 1;
  }

  // ---- epilogue: gates + combine, LDS-transposed for 128B-line stores ----
  // acc C/D mapping (m89): col = lane&15 (=lr), row = kg*4 + r (+mi*16).
  // Per wave: private 32x33 f32 buffer (4224B); 8 waves = 33 KiB from smem[0].
  float* tb = (float*)smem + wid * (32 * 33);
  const float ba_[2] = { ba[n0 + wn * 32 + lr], ba[n0 + wn * 32 + 16 + lr] };
  const float bk_[2] = { bk[n0 + wn * 32 + lr], bk[n0 + wn * 32 + 16 + lr] };
  const float bv_[2] = { bv[n0 + wn * 32 + lr], bv[n0 + wn * 32 + 16 + lr] };

#pragma unroll 1
  for (int arr = 0; arr < 2; ++arr) {
    float* dst = arr ? Bwr : Aret;
#pragma unroll 1
    for (int half = 0; half < 2; ++half) {
      // write pass: 16 values into [row_local][col]
#pragma unroll
      for (int ni = 0; ni < 2; ++ni)
#pragma unroll
        for (int m2 = 0; m2 < 2; ++m2) {
          const int mi = half * 2 + m2;
#pragma unroll
          for (int r = 0; r < 4; ++r) {
            float za = acc[0][mi][ni][r] + ba_[ni];
            float zk = acc[1][mi][ni][r] + bk_[ni];
            float val;
            if (arr == 0) {
              val = sigmoidf_(za) * (1.f - sigmoidf_(zk));
            } else {
              float zv = acc[2][mi][ni][r] + bv_[ni];
              val = sigmoidf_(zk) * tanhf_(zv);
            }
            tb[(m2 * 16 + kg * 4 + r) * 33 + ni * 16 + lr] = val;
          }
        }
      __syncthreads();
      // read+store pass: 4 instrs, each 8 rows x 128B fully-covered lines
#pragma unroll
      for (int i = 0; i < 4; ++i) {
        const int rl = i * 8 + (lane >> 3);            // 0..31
        const int cc = (lane & 7) * 4;                 // 0..28
        float4 v;
        v.x = tb[rl * 33 + cc + 0];
        v.y = tb[rl * 33 + cc + 1];
        v.z = tb[rl * 33 + cc + 2];
        v.w = tb[rl * 33 + cc + 3];
        const size_t m = (size_t)(m0 + wm * 64 + half * 32 + rl);
        *(float4*)&dst[m * D_DIM + n0 + wn * 32 + cc] = v;
      }
      __syncthreads();
    }
  }
}

// ---------------- float4 helpers ----------------
__device__ __forceinline__ float4 f4fma(float4 a, float4 h, float4 b) {
  float4 r;
  r.x = fmaf(a.x, h.x, b.x); r.y = fmaf(a.y, h.y, b.y);
  r.z = fmaf(a.z, h.z, b.z); r.w = fmaf(a.w, h.w, b.w);
  return r;
}
__device__ __forceinline__ float4 f4mul(float4 a, float4 b) {
  float4 r; r.x = a.x*b.x; r.y = a.y*b.y; r.z = a.z*b.z; r.w = a.w*b.w; return r;
}

// ---------------- scan phase 1: per-chunk affine composition ----------------
__global__ void scan_phase1(const float4* __restrict__ A4, const float4* __restrict__ B4,
                            float4* __restrict__ cP, float4* __restrict__ cS) {
  int tid = blockIdx.x * 256 + threadIdx.x;       // c*BD4 + bd4
  int bd4 = tid & (BD4 - 1);
  int c   = tid >> 12;
  size_t base = (size_t)c * LCH * BD4 + bd4;
  float4 P = make_float4(1.f, 1.f, 1.f, 1.f);
  float4 S = make_float4(0.f, 0.f, 0.f, 0.f);
#pragma unroll 4
  for (int t = 0; t < LCH; ++t) {
    float4 a = A4[base + (size_t)t * BD4];
    float4 b = B4[base + (size_t)t * BD4];
    S = f4fma(a, S, b);
    P = f4mul(P, a);
  }
  cP[tid] = P;
  cS[tid] = S;
}

// ---------------- scan phase 2: scan 64 chunk summaries per state ----------------
__global__ void scan_phase2(const float4* __restrict__ h0q,
                            const float4* __restrict__ cP, const float4* __restrict__ cS,
                            float4* __restrict__ hst, float4* __restrict__ houtq) {
  int bd4 = blockIdx.x * 64 + threadIdx.x;        // 0..BD4-1 (64 blocks x 64)
  float4 h = h0q[bd4];
  houtq[bd4] = h;                                  // h[0] = h0
#pragma unroll 4
  for (int c = 0; c < CCH; ++c) {
    hst[(size_t)c * BD4 + bd4] = h;
    h = f4fma(cP[(size_t)c * BD4 + bd4], h, cS[(size_t)c * BD4 + bd4]);
  }
}

// ---------------- scan phase 3: replay chunks, write h and output ----------------
// Aq = out region (holds a, overwritten with output); Bq = hout[BD:] (holds b,
// overwritten with h). Disjoint regions; per-address read-once-then-write by
// the same thread.
__global__ void scan_phase3(const float4* __restrict__ hst,
                            float4* __restrict__ Aq, float4* __restrict__ Bq) {
  int tid = blockIdx.x * 256 + threadIdx.x;
  int bd4 = tid & (BD4 - 1);
  int c   = tid >> 12;
  size_t base = (size_t)c * LCH * BD4 + bd4;
  float4 h = hst[(size_t)c * BD4 + bd4];
#pragma unroll 4
  for (int t = 0; t < LCH; ++t) {
    size_t off = base + (size_t)t * BD4;
    float4 a = Aq[off];
    float4 b = Bq[off];
    h = f4fma(a, h, b);
    Bq[off] = h;                                   // h[(c*LCH+t)+1]
    float4 o;
    o.x = h.x * h.x * sigmoidf_(h.x);
    o.y = h.y * h.y * sigmoidf_(h.y);
    o.z = h.z * h.z * sigmoidf_(h.z);
    o.w = h.w * h.w * sigmoidf_(h.w);
    Aq[off] = o;                                   // hs^2 * sigmoid(hs)
  }
}

extern "C" void kernel_launch(void* const* d_in, const int* in_sizes, int n_in,
                              void* d_out, int out_size, void* d_ws, size_t ws_size,
                              hipStream_t stream) {
  const float* x  = (const float*)d_in[0];
  const float* h0 = (const float*)d_in[1];
  const float* Wa = (const float*)d_in[2];
  const float* ba = (const float*)d_in[3];
  const float* Wk = (const float*)d_in[4];
  const float* bk = (const float*)d_in[5];
  const float* Wv = (const float*)d_in[6];
  const float* bv = (const float*)d_in[7];

  float* out  = (float*)d_out;                       // [T,B,D]
  float* hout = out + (size_t)M_DIM * D_DIM;         // [T+1,B,D]

  // Big intermediates alias d_out (overwritten in place by scan_phase3):
  float* Aret = out;              // retain a_t  -> out region
  float* Bwr  = hout + BD;        // write  b_t  -> hout[1:] region

  // workspace (~70 MiB): x16 (64Mi, reused by cP/cS/hst) + fp16 weights (6Mi)
  char* ws = (char*)d_ws;
  _Float16* x16  = (_Float16*)ws;
  _Float16* wa16 = (_Float16*)(ws + 67108864);
  _Float16* wk16 = (_Float16*)(ws + 67108864 + 2097152);
  _Float16* wv16 = (_Float16*)(ws + 67108864 + 2 * 2097152);
  float4* cP  = (float4*)ws;                // x16 dead after gate_gemm
  float4* cS  = cP + (size_t)CCH * BD4;     // +4 MiB
  float4* hst = cS + (size_t)CCH * BD4;     // +4 MiB

  const int nx8 = M_DIM * D_DIM / 8;
  const int nw8 = D_DIM * D_DIM / 8;
  cvt_f32_f16<<<dim3((nx8 + 255) / 256), dim3(256), 0, stream>>>(x, x16, nx8);
  cvt_f32_f16<<<dim3((nw8 + 255) / 256), dim3(256), 0, stream>>>(Wa, wa16, nw8);
  cvt_f32_f16<<<dim3((nw8 + 255) / 256), dim3(256), 0, stream>>>(Wk, wk16, nw8);
  cvt_f32_f16<<<dim3((nw8 + 255) / 256), dim3(256), 0, stream>>>(Wv, wv16, nw8);

  gate_gemm<<<dim3(M_DIM / 128, D_DIM / 128), dim3(512), 0, stream>>>(
      x16, wa16, wk16, wv16, ba, bk, bv, Aret, Bwr);

  scan_phase1<<<dim3(CCH * BD4 / 256), dim3(256), 0, stream>>>(
      (const float4*)Aret, (const float4*)Bwr, cP, cS);
  scan_phase2<<<dim3(BD4 / 64), dim3(64), 0, stream>>>(
      (const float4*)h0, cP, cS, hst, (float4*)hout);
  scan_phase3<<<dim3(CCH * BD4 / 256), dim3(256), 0, stream>>>(
      hst, (float4*)Aret, (float4*)Bwr);
}

// Round 5
// 784.094 us; speedup vs baseline: 3.3304x; 3.3304x over previous
//
#include <hip/hip_runtime.h>
#include <cstdint>

#define T_DIM 2048
#define B_DIM 16
#define D_DIM 1024
#define M_DIM (T_DIM * B_DIM)        // 32768 rows
#define BD (B_DIM * D_DIM)           // 16384 independent scan states
#define BD4 (BD / 4)                 // 4096 float4 columns
#define CCH 64                       // scan chunks
#define LCH (T_DIM / CCH)            // 32 steps per chunk

typedef _Float16 f16x8 __attribute__((ext_vector_type(8)));
typedef float f32x4 __attribute__((ext_vector_type(4)));

// async global -> LDS, 16B per lane. LDS dest must be wave-uniform base +
// lane*16 (tid*16 satisfies this per 64-lane wave). Dest is LINEAR; the
// bank-conflict swizzle is applied on the SOURCE address + the LDS READ
// (same XOR involution on both sides — guide rule #21).
__device__ __forceinline__ void async_cp16(const void* g, void* l) {
  __builtin_amdgcn_global_load_lds(
      (const __attribute__((address_space(1))) void*)(uintptr_t)g,
      (__attribute__((address_space(3))) void*)(uint32_t)(uintptr_t)l,
      16, 0, 0);
}

__device__ __forceinline__ float sigmoidf_(float z) {
  return 1.f / (1.f + __expf(-z));
}
__device__ __forceinline__ float tanhf_(float z) {
  float t = __expf(2.f * z);
  return (t - 1.f) / (t + 1.f);
}

// ---------------- f32 -> f16 convert, 8 elems/thread ----------------
__global__ void cvt_f32_f16(const float* __restrict__ s, _Float16* __restrict__ d, int n8) {
  int i = blockIdx.x * blockDim.x + threadIdx.x;
  if (i >= n8) return;
  const float4* sp = (const float4*)s;
  float4 u = sp[2 * i];
  float4 v = sp[2 * i + 1];
  f16x8 o;
  o[0] = (_Float16)u.x; o[1] = (_Float16)u.y; o[2] = (_Float16)u.z; o[3] = (_Float16)u.w;
  o[4] = (_Float16)v.x; o[5] = (_Float16)v.y; o[6] = (_Float16)v.z; o[7] = (_Float16)v.w;
  *(f16x8*)(d + (size_t)i * 8) = o;
}

// ---------------- fused 3-gate GEMM + gate combine ----------------
// Tile 128x128, BK=32, 8 waves (2x4), wave tile 64x32, mfma 16x16x32 f16.
// LDS rows are 64B (32 f16): 4 chunks of 16B. Swizzle: chunk' = chunk ^ ((row>>1)&3)
// (verified: BANK_CONFLICT 2.1e7 -> 2.1e6 in round 4).
// Epilogue loops are FULLY unrolled: any runtime index into acc sends the
// whole accumulator to scratch (rule #20 — round 4's 13 GB WRITE_SIZE bug).
__global__ __launch_bounds__(512, 2) void gate_gemm(
    const _Float16* __restrict__ x16,
    const _Float16* __restrict__ wa16,
    const _Float16* __restrict__ wk16,
    const _Float16* __restrict__ wv16,
    const float* __restrict__ ba, const float* __restrict__ bk, const float* __restrict__ bv,
    float* __restrict__ Aret, float* __restrict__ Bwr) {
  __shared__ __align__(16) char smem[65536];
  // [0, 16Ki)  : sA[2][128][32] f16
  // [16Ki,64Ki): sB[2][3][128][32] f16
  // epilogue   : tb = per-wave 32x33 f32 transpose buffers from offset 0 (33 KiB)
  auto sA = (_Float16 (*)[128][32])(smem);
  auto sB = (_Float16 (*)[3][128][32])(smem + 16384);

  const int tid  = threadIdx.x;
  const int wid  = tid >> 6;
  const int lane = tid & 63;
  const int wm = wid >> 2;    // 0..1 : 64-row slab
  const int wn = wid & 3;     // 0..3 : 32-col slab
  const int lr = lane & 15;
  const int kg = lane >> 4;

  const int m0 = blockIdx.x * 128;
  const int n0 = blockIdx.y * 128;

  const int arow = tid >> 2;                      // 0..127
  const int achk = tid & 3;                       // LDS slot this lane fills
  const int aswz = achk ^ ((arow >> 1) & 3);      // global chunk that belongs there

  f32x4 acc[3][4][2];
#pragma unroll
  for (int w = 0; w < 3; ++w)
#pragma unroll
    for (int mi = 0; mi < 4; ++mi)
#pragma unroll
      for (int ni = 0; ni < 2; ++ni)
        acc[w][mi][ni] = (f32x4)0.f;

  const size_t gA0 = (size_t)(m0 + arow) * D_DIM + aswz * 8;
  const size_t gB0 = (size_t)(n0 + arow) * D_DIM + aswz * 8;

  auto stage = [&](int buf, int kk) {
    async_cp16(x16  + gA0 + kk * 32, (char*)&sA[buf][0][0]    + tid * 16);
    async_cp16(wa16 + gB0 + kk * 32, (char*)&sB[buf][0][0][0] + tid * 16);
    async_cp16(wk16 + gB0 + kk * 32, (char*)&sB[buf][1][0][0] + tid * 16);
    async_cp16(wv16 + gB0 + kk * 32, (char*)&sB[buf][2][0][0] + tid * 16);
  };

  const int slot = (kg ^ ((lr >> 1) & 3)) * 8;    // swizzled 16B slot (8 f16)

  auto compute = [&](int buf) {
    f16x8 af[4];
#pragma unroll
    for (int mi = 0; mi < 4; ++mi)
      af[mi] = *(const f16x8*)&sA[buf][wm * 64 + mi * 16 + lr][slot];
#pragma unroll
    for (int w = 0; w < 3; ++w) {
      f16x8 b0 = *(const f16x8*)&sB[buf][w][wn * 32 + lr][slot];
      f16x8 b1 = *(const f16x8*)&sB[buf][w][wn * 32 + 16 + lr][slot];
#pragma unroll
      for (int mi = 0; mi < 4; ++mi) {
        acc[w][mi][0] = __builtin_amdgcn_mfma_f32_16x16x32_f16(af[mi], b0, acc[w][mi][0], 0, 0, 0);
        acc[w][mi][1] = __builtin_amdgcn_mfma_f32_16x16x32_f16(af[mi], b1, acc[w][mi][1], 0, 0, 0);
      }
    }
  };

  stage(0, 0);
  __syncthreads();
  int cur = 0;
#pragma unroll 1
  for (int kk = 0; kk < 32; ++kk) {
    if (kk + 1 < 32) stage(cur ^ 1, kk + 1);  // next-tile loads fly under MFMA
    compute(cur);
    __syncthreads();                           // drains vmcnt+lgkmcnt
    cur ^= 1;
  }

  // ---- epilogue: gates + combine, LDS-transposed for 128B-line stores ----
  // acc C/D mapping (m89): col = lane&15 (=lr), row = kg*4 + r (+mi*16).
  // Per wave: private 32x33 f32 buffer (4224B); 8 waves = 33 KiB from smem[0].
  // ALL loops fully unrolled -> every acc index compile-time constant.
  float* tb = (float*)smem + wid * (32 * 33);
  const float ba_[2] = { ba[n0 + wn * 32 + lr], ba[n0 + wn * 32 + 16 + lr] };
  const float bk_[2] = { bk[n0 + wn * 32 + lr], bk[n0 + wn * 32 + 16 + lr] };
  const float bv_[2] = { bv[n0 + wn * 32 + lr], bv[n0 + wn * 32 + 16 + lr] };

#pragma unroll
  for (int arr = 0; arr < 2; ++arr) {
    float* dst = arr ? Bwr : Aret;
#pragma unroll
    for (int half = 0; half < 2; ++half) {
      // write pass: 16 values into [row_local][col]
#pragma unroll
      for (int ni = 0; ni < 2; ++ni)
#pragma unroll
        for (int m2 = 0; m2 < 2; ++m2) {
          const int mi = half * 2 + m2;
#pragma unroll
          for (int r = 0; r < 4; ++r) {
            float za = acc[0][mi][ni][r] + ba_[ni];
            float zk = acc[1][mi][ni][r] + bk_[ni];
            float val;
            if (arr == 0) {
              val = sigmoidf_(za) * (1.f - sigmoidf_(zk));
            } else {
              float zv = acc[2][mi][ni][r] + bv_[ni];
              val = sigmoidf_(zk) * tanhf_(zv);
            }
            tb[(m2 * 16 + kg * 4 + r) * 33 + ni * 16 + lr] = val;
          }
        }
      __syncthreads();
      // read+store pass: 4 instrs, each 8 rows x 128B fully-covered lines
#pragma unroll
      for (int i = 0; i < 4; ++i) {
        const int rl = i * 8 + (lane >> 3);            // 0..31
        const int cc = (lane & 7) * 4;                 // 0..28
        float4 v;
        v.x = tb[rl * 33 + cc + 0];
        v.y = tb[rl * 33 + cc + 1];
        v.z = tb[rl * 33 + cc + 2];
        v.w = tb[rl * 33 + cc + 3];
        const size_t m = (size_t)(m0 + wm * 64 + half * 32 + rl);
        *(float4*)&dst[m * D_DIM + n0 + wn * 32 + cc] = v;
      }
      __syncthreads();
    }
  }
}

// ---------------- float4 helpers ----------------
__device__ __forceinline__ float4 f4fma(float4 a, float4 h, float4 b) {
  float4 r;
  r.x = fmaf(a.x, h.x, b.x); r.y = fmaf(a.y, h.y, b.y);
  r.z = fmaf(a.z, h.z, b.z); r.w = fmaf(a.w, h.w, b.w);
  return r;
}
__device__ __forceinline__ float4 f4mul(float4 a, float4 b) {
  float4 r; r.x = a.x*b.x; r.y = a.y*b.y; r.z = a.z*b.z; r.w = a.w*b.w; return r;
}

// ---------------- scan phase 1: per-chunk affine composition ----------------
__global__ void scan_phase1(const float4* __restrict__ A4, const float4* __restrict__ B4,
                            float4* __restrict__ cP, float4* __restrict__ cS) {
  int tid = blockIdx.x * 256 + threadIdx.x;       // c*BD4 + bd4
  int bd4 = tid & (BD4 - 1);
  int c   = tid >> 12;
  size_t base = (size_t)c * LCH * BD4 + bd4;
  float4 P = make_float4(1.f, 1.f, 1.f, 1.f);
  float4 S = make_float4(0.f, 0.f, 0.f, 0.f);
#pragma unroll 4
  for (int t = 0; t < LCH; ++t) {
    float4 a = A4[base + (size_t)t * BD4];
    float4 b = B4[base + (size_t)t * BD4];
    S = f4fma(a, S, b);
    P = f4mul(P, a);
  }
  cP[tid] = P;
  cS[tid] = S;
}

// ---------------- scan phase 2: scan 64 chunk summaries per state ----------------
__global__ void scan_phase2(const float4* __restrict__ h0q,
                            const float4* __restrict__ cP, const float4* __restrict__ cS,
                            float4* __restrict__ hst, float4* __restrict__ houtq) {
  int bd4 = blockIdx.x * 64 + threadIdx.x;        // 0..BD4-1 (64 blocks x 64)
  float4 h = h0q[bd4];
  houtq[bd4] = h;                                  // h[0] = h0
#pragma unroll 4
  for (int c = 0; c < CCH; ++c) {
    hst[(size_t)c * BD4 + bd4] = h;
    h = f4fma(cP[(size_t)c * BD4 + bd4], h, cS[(size_t)c * BD4 + bd4]);
  }
}

// ---------------- scan phase 3: replay chunks, write h and output ----------------
// Aq = out region (holds a, overwritten with output); Bq = hout[BD:] (holds b,
// overwritten with h). Disjoint regions; per-address read-once-then-write by
// the same thread.
__global__ void scan_phase3(const float4* __restrict__ hst,
                            float4* __restrict__ Aq, float4* __restrict__ Bq) {
  int tid = blockIdx.x * 256 + threadIdx.x;
  int bd4 = tid & (BD4 - 1);
  int c   = tid >> 12;
  size_t base = (size_t)c * LCH * BD4 + bd4;
  float4 h = hst[(size_t)c * BD4 + bd4];
#pragma unroll 4
  for (int t = 0; t < LCH; ++t) {
    size_t off = base + (size_t)t * BD4;
    float4 a = Aq[off];
    float4 b = Bq[off];
    h = f4fma(a, h, b);
    Bq[off] = h;                                   // h[(c*LCH+t)+1]
    float4 o;
    o.x = h.x * h.x * sigmoidf_(h.x);
    o.y = h.y * h.y * sigmoidf_(h.y);
    o.z = h.z * h.z * sigmoidf_(h.z);
    o.w = h.w * h.w * sigmoidf_(h.w);
    Aq[off] = o;                                   // hs^2 * sigmoid(hs)
  }
}

extern "C" void kernel_launch(void* const* d_in, const int* in_sizes, int n_in,
                              void* d_out, int out_size, void* d_ws, size_t ws_size,
                              hipStream_t stream) {
  const float* x  = (const float*)d_in[0];
  const float* h0 = (const float*)d_in[1];
  const float* Wa = (const float*)d_in[2];
  const float* ba = (const float*)d_in[3];
  const float* Wk = (const float*)d_in[4];
  const float* bk = (const float*)d_in[5];
  const float* Wv = (const float*)d_in[6];
  const float* bv = (const float*)d_in[7];

  float* out  = (float*)d_out;                       // [T,B,D]
  float* hout = out + (size_t)M_DIM * D_DIM;         // [T+1,B,D]

  // Big intermediates alias d_out (overwritten in place by scan_phase3):
  float* Aret = out;              // retain a_t  -> out region
  float* Bwr  = hout + BD;        // write  b_t  -> hout[1:] region

  // workspace (~70 MiB): x16 (64Mi, reused by cP/cS/hst) + fp16 weights (6Mi)
  char* ws = (char*)d_ws;
  _Float16* x16  = (_Float16*)ws;
  _Float16* wa16 = (_Float16*)(ws + 67108864);
  _Float16* wk16 = (_Float16*)(ws + 67108864 + 2097152);
  _Float16* wv16 = (_Float16*)(ws + 67108864 + 2 * 2097152);
  float4* cP  = (float4*)ws;                // x16 dead after gate_gemm
  float4* cS  = cP + (size_t)CCH * BD4;     // +4 MiB
  float4* hst = cS + (size_t)CCH * BD4;     // +4 MiB

  const int nx8 = M_DIM * D_DIM / 8;
  const int nw8 = D_DIM * D_DIM / 8;
  cvt_f32_f16<<<dim3((nx8 + 255) / 256), dim3(256), 0, stream>>>(x, x16, nx8);
  cvt_f32_f16<<<dim3((nw8 + 255) / 256), dim3(256), 0, stream>>>(Wa, wa16, nw8);
  cvt_f32_f16<<<dim3((nw8 + 255) / 256), dim3(256), 0, stream>>>(Wk, wk16, nw8);
  cvt_f32_f16<<<dim3((nw8 + 255) / 256), dim3(256), 0, stream>>>(Wv, wv16, nw8);

  gate_gemm<<<dim3(M_DIM / 128, D_DIM / 128), dim3(512), 0, stream>>>(
      x16, wa16, wk16, wv16, ba, bk, bv, Aret, Bwr);

  scan_phase1<<<dim3(CCH * BD4 / 256), dim3(256), 0, stream>>>(
      (const float4*)Aret, (const float4*)Bwr, cP, cS);
  scan_phase2<<<dim3(BD4 / 64), dim3(64), 0, stream>>>(
      (const float4*)h0, cP, cS, hst, (float4*)hout);
  scan_phase3<<<dim3(CCH * BD4 / 256), dim3(256), 0, stream>>>(
      hst, (float4*)Aret, (float4*)Bwr);
}

// Round 6
// 764.592 us; speedup vs baseline: 3.4153x; 1.0255x over previous
//
#include <hip/hip_runtime.h>
#include <cstdint>

#define T_DIM 2048
#define B_DIM 16
#define D_DIM 1024
#define M_DIM (T_DIM * B_DIM)        // 32768 rows
#define BD (B_DIM * D_DIM)           // 16384 independent scan states
#define BD4 (BD / 4)                 // 4096 float4 columns
#define CCH 64                       // scan chunks
#define LCH (T_DIM / CCH)            // 32 steps per chunk

typedef _Float16 f16x8 __attribute__((ext_vector_type(8)));
typedef float f32x4 __attribute__((ext_vector_type(4)));

// async global -> LDS, 16B per lane. LDS dest must be wave-uniform base +
// lane*16 (tid*16 satisfies this per 64-lane wave). Dest is LINEAR; the
// bank-conflict swizzle is applied on the SOURCE address + the LDS READ
// (same XOR involution on both sides — guide rule #21).
__device__ __forceinline__ void async_cp16(const void* g, void* l) {
  __builtin_amdgcn_global_load_lds(
      (const __attribute__((address_space(1))) void*)(uintptr_t)g,
      (__attribute__((address_space(3))) void*)(uint32_t)(uintptr_t)l,
      16, 0, 0);
}

__device__ __forceinline__ float sigmoidf_(float z) {
  return 1.f / (1.f + __expf(-z));
}
__device__ __forceinline__ float tanhf_(float z) {
  float t = __expf(2.f * z);
  return (t - 1.f) / (t + 1.f);
}

// ---------------- f32 -> f16 convert, 8 elems/thread ----------------
__global__ void cvt_f32_f16(const float* __restrict__ s, _Float16* __restrict__ d, int n8) {
  int i = blockIdx.x * blockDim.x + threadIdx.x;
  if (i >= n8) return;
  const float4* sp = (const float4*)s;
  float4 u = sp[2 * i];
  float4 v = sp[2 * i + 1];
  f16x8 o;
  o[0] = (_Float16)u.x; o[1] = (_Float16)u.y; o[2] = (_Float16)u.z; o[3] = (_Float16)u.w;
  o[4] = (_Float16)v.x; o[5] = (_Float16)v.y; o[6] = (_Float16)v.z; o[7] = (_Float16)v.w;
  *(f16x8*)(d + (size_t)i * 8) = o;
}

// ---------------- fused 3-gate GEMM + gate combine ----------------
// Tile 128x128, BK=32, 8 waves (2x4), wave tile 64x32, mfma 16x16x32 f16.
// LDS: 3 buffers x 32 KB (sA 8 KB + sB 24 KB each), depth-2 prefetch with
// counted vmcnt (T3/T4): loads for tiles k+1,k+2 stay in flight across the
// barrier; only the 4 oldest (tile k's) must have landed -> vmcnt(8).
// Swizzle: chunk' = chunk ^ ((row>>1)&3) (verified: conflicts 2.1e7 -> 2.1e6).
// Epilogue fully unrolled (rule #20: runtime acc index -> scratch disaster).
__global__ __launch_bounds__(512, 2) void gate_gemm(
    const _Float16* __restrict__ x16,
    const _Float16* __restrict__ wa16,
    const _Float16* __restrict__ wk16,
    const _Float16* __restrict__ wv16,
    const float* __restrict__ ba, const float* __restrict__ bk, const float* __restrict__ bv,
    float* __restrict__ Aret, float* __restrict__ Bwr) {
  __shared__ __align__(16) char smem[98304];
  // buf b at smem + b*32768: A[128][32] f16 (8 KB) then B[3][128][32] (24 KB)
  // epilogue: tb = per-wave 32x33 f32 transpose buffers from smem[0] (33 KiB)

  const int tid  = threadIdx.x;
  const int wid  = tid >> 6;
  const int lane = tid & 63;
  const int wm = wid >> 2;    // 0..1 : 64-row slab
  const int wn = wid & 3;     // 0..3 : 32-col slab
  const int lr = lane & 15;
  const int kg = lane >> 4;

  const int m0 = blockIdx.x * 128;
  const int n0 = blockIdx.y * 128;

  const int arow = tid >> 2;                      // 0..127
  const int achk = tid & 3;                       // LDS slot this lane fills
  const int aswz = achk ^ ((arow >> 1) & 3);      // global chunk that belongs there

  f32x4 acc[3][4][2];
#pragma unroll
  for (int w = 0; w < 3; ++w)
#pragma unroll
    for (int mi = 0; mi < 4; ++mi)
#pragma unroll
      for (int ni = 0; ni < 2; ++ni)
        acc[w][mi][ni] = (f32x4)0.f;

  const size_t gA0 = (size_t)(m0 + arow) * D_DIM + aswz * 8;
  const size_t gB0 = (size_t)(n0 + arow) * D_DIM + aswz * 8;

  auto stage = [&](int buf, int kk) {
    char* base = smem + buf * 32768;
    async_cp16(x16  + gA0 + kk * 32, base         + tid * 16);
    async_cp16(wa16 + gB0 + kk * 32, base +  8192 + tid * 16);
    async_cp16(wk16 + gB0 + kk * 32, base + 16384 + tid * 16);
    async_cp16(wv16 + gB0 + kk * 32, base + 24576 + tid * 16);
  };

  const int slot = (kg ^ ((lr >> 1) & 3)) * 8;    // swizzled 16B slot (8 f16)

  auto compute = [&](int buf) {
    const _Float16* bufA = (const _Float16*)(smem + buf * 32768);
    const _Float16* bufB = bufA + 4096;           // +8 KB
    f16x8 af[4];
#pragma unroll
    for (int mi = 0; mi < 4; ++mi)
      af[mi] = *(const f16x8*)&bufA[(wm * 64 + mi * 16 + lr) * 32 + slot];
#pragma unroll
    for (int w = 0; w < 3; ++w) {
      f16x8 b0 = *(const f16x8*)&bufB[(w * 128 + wn * 32 + lr) * 32 + slot];
      f16x8 b1 = *(const f16x8*)&bufB[(w * 128 + wn * 32 + 16 + lr) * 32 + slot];
#pragma unroll
      for (int mi = 0; mi < 4; ++mi) {
        acc[w][mi][0] = __builtin_amdgcn_mfma_f32_16x16x32_f16(af[mi], b0, acc[w][mi][0], 0, 0, 0);
        acc[w][mi][1] = __builtin_amdgcn_mfma_f32_16x16x32_f16(af[mi], b1, acc[w][mi][1], 0, 0, 0);
      }
    }
  };

  // ---- pipelined K-loop: depth-2 prefetch, counted vmcnt, raw barriers ----
  stage(0, 0);
  stage(1, 1);
#pragma unroll 1
  for (int kk = 0; kk < 30; ++kk) {
    stage((kk + 2) % 3, kk + 2);                   // tile k+2 in flight
    asm volatile("s_waitcnt vmcnt(8)" ::: "memory");   // tile k's 4 loads landed
    __builtin_amdgcn_s_barrier();                  // ... in ALL waves
    compute(kk % 3);
    asm volatile("s_waitcnt lgkmcnt(0)" ::: "memory"); // ds_reads retired
    __builtin_amdgcn_s_barrier();                  // buffer may be overwritten
  }
  // kk = 30 (no new stage; outstanding = tiles 30,31)
  asm volatile("s_waitcnt vmcnt(4)" ::: "memory");
  __builtin_amdgcn_s_barrier();
  compute(0);
  asm volatile("s_waitcnt lgkmcnt(0)" ::: "memory");
  __builtin_amdgcn_s_barrier();
  // kk = 31
  asm volatile("s_waitcnt vmcnt(0)" ::: "memory");
  __builtin_amdgcn_s_barrier();
  compute(1);
  asm volatile("s_waitcnt lgkmcnt(0)" ::: "memory");
  __builtin_amdgcn_s_barrier();

  // ---- epilogue: gates + combine, LDS-transposed for 128B-line stores ----
  // acc C/D mapping (m89): col = lane&15 (=lr), row = kg*4 + r (+mi*16).
  // Per wave: private 32x33 f32 buffer (4224B); 8 waves = 33 KiB from smem[0].
  float* tb = (float*)smem + wid * (32 * 33);
  const float ba_[2] = { ba[n0 + wn * 32 + lr], ba[n0 + wn * 32 + 16 + lr] };
  const float bk_[2] = { bk[n0 + wn * 32 + lr], bk[n0 + wn * 32 + 16 + lr] };
  const float bv_[2] = { bv[n0 + wn * 32 + lr], bv[n0 + wn * 32 + 16 + lr] };

#pragma unroll
  for (int arr = 0; arr < 2; ++arr) {
    float* dst = arr ? Bwr : Aret;
#pragma unroll
    for (int half = 0; half < 2; ++half) {
      // write pass: 16 values into [row_local][col]
#pragma unroll
      for (int ni = 0; ni < 2; ++ni)
#pragma unroll
        for (int m2 = 0; m2 < 2; ++m2) {
          const int mi = half * 2 + m2;
#pragma unroll
          for (int r = 0; r < 4; ++r) {
            float za = acc[0][mi][ni][r] + ba_[ni];
            float zk = acc[1][mi][ni][r] + bk_[ni];
            float val;
            if (arr == 0) {
              val = sigmoidf_(za) * (1.f - sigmoidf_(zk));
            } else {
              float zv = acc[2][mi][ni][r] + bv_[ni];
              val = sigmoidf_(zk) * tanhf_(zv);
            }
            tb[(m2 * 16 + kg * 4 + r) * 33 + ni * 16 + lr] = val;
          }
        }
      __syncthreads();
      // read+store pass: 4 instrs, each 8 rows x 128B fully-covered lines
#pragma unroll
      for (int i = 0; i < 4; ++i) {
        const int rl = i * 8 + (lane >> 3);            // 0..31
        const int cc = (lane & 7) * 4;                 // 0..28
        float4 v;
        v.x = tb[rl * 33 + cc + 0];
        v.y = tb[rl * 33 + cc + 1];
        v.z = tb[rl * 33 + cc + 2];
        v.w = tb[rl * 33 + cc + 3];
        const size_t m = (size_t)(m0 + wm * 64 + half * 32 + rl);
        *(float4*)&dst[m * D_DIM + n0 + wn * 32 + cc] = v;
      }
      __syncthreads();
    }
  }
}

// ---------------- float4 helpers ----------------
__device__ __forceinline__ float4 f4fma(float4 a, float4 h, float4 b) {
  float4 r;
  r.x = fmaf(a.x, h.x, b.x); r.y = fmaf(a.y, h.y, b.y);
  r.z = fmaf(a.z, h.z, b.z); r.w = fmaf(a.w, h.w, b.w);
  return r;
}
__device__ __forceinline__ float4 f4mul(float4 a, float4 b) {
  float4 r; r.x = a.x*b.x; r.y = a.y*b.y; r.z = a.z*b.z; r.w = a.w*b.w; return r;
}

// ---------------- scan phase 1: per-chunk affine composition ----------------
__global__ void scan_phase1(const float4* __restrict__ A4, const float4* __restrict__ B4,
                            float4* __restrict__ cP, float4* __restrict__ cS) {
  int tid = blockIdx.x * 256 + threadIdx.x;       // c*BD4 + bd4
  int bd4 = tid & (BD4 - 1);
  int c   = tid >> 12;
  size_t base = (size_t)c * LCH * BD4 + bd4;
  float4 P = make_float4(1.f, 1.f, 1.f, 1.f);
  float4 S = make_float4(0.f, 0.f, 0.f, 0.f);
#pragma unroll 4
  for (int t = 0; t < LCH; ++t) {
    float4 a = A4[base + (size_t)t * BD4];
    float4 b = B4[base + (size_t)t * BD4];
    S = f4fma(a, S, b);
    P = f4mul(P, a);
  }
  cP[tid] = P;
  cS[tid] = S;
}

// ---------------- scan phase 2: scan 64 chunk summaries per state ----------------
__global__ void scan_phase2(const float4* __restrict__ h0q,
                            const float4* __restrict__ cP, const float4* __restrict__ cS,
                            float4* __restrict__ hst, float4* __restrict__ houtq) {
  int bd4 = blockIdx.x * 64 + threadIdx.x;        // 0..BD4-1 (64 blocks x 64)
  float4 h = h0q[bd4];
  houtq[bd4] = h;                                  // h[0] = h0
#pragma unroll 4
  for (int c = 0; c < CCH; ++c) {
    hst[(size_t)c * BD4 + bd4] = h;
    h = f4fma(cP[(size_t)c * BD4 + bd4], h, cS[(size_t)c * BD4 + bd4]);
  }
}

// ---------------- scan phase 3: replay chunks, write h and output ----------------
// Aq = out region (holds a, overwritten with output); Bq = hout[BD:] (holds b,
// overwritten with h). Disjoint regions; per-address read-once-then-write by
// the same thread.
__global__ void scan_phase3(const float4* __restrict__ hst,
                            float4* __restrict__ Aq, float4* __restrict__ Bq) {
  int tid = blockIdx.x * 256 + threadIdx.x;
  int bd4 = tid & (BD4 - 1);
  int c   = tid >> 12;
  size_t base = (size_t)c * LCH * BD4 + bd4;
  float4 h = hst[(size_t)c * BD4 + bd4];
#pragma unroll 4
  for (int t = 0; t < LCH; ++t) {
    size_t off = base + (size_t)t * BD4;
    float4 a = Aq[off];
    float4 b = Bq[off];
    h = f4fma(a, h, b);
    Bq[off] = h;                                   // h[(c*LCH+t)+1]
    float4 o;
    o.x = h.x * h.x * sigmoidf_(h.x);
    o.y = h.y * h.y * sigmoidf_(h.y);
    o.z = h.z * h.z * sigmoidf_(h.z);
    o.w = h.w * h.w * sigmoidf_(h.w);
    Aq[off] = o;                                   // hs^2 * sigmoid(hs)
  }
}

extern "C" void kernel_launch(void* const* d_in, const int* in_sizes, int n_in,
                              void* d_out, int out_size, void* d_ws, size_t ws_size,
                              hipStream_t stream) {
  const float* x  = (const float*)d_in[0];
  const float* h0 = (const float*)d_in[1];
  const float* Wa = (const float*)d_in[2];
  const float* ba = (const float*)d_in[3];
  const float* Wk = (const float*)d_in[4];
  const float* bk = (const float*)d_in[5];
  const float* Wv = (const float*)d_in[6];
  const float* bv = (const float*)d_in[7];

  float* out  = (float*)d_out;                       // [T,B,D]
  float* hout = out + (size_t)M_DIM * D_DIM;         // [T+1,B,D]

  // Big intermediates alias d_out (overwritten in place by scan_phase3):
  float* Aret = out;              // retain a_t  -> out region
  float* Bwr  = hout + BD;        // write  b_t  -> hout[1:] region

  // workspace (~70 MiB): x16 (64Mi, reused by cP/cS/hst) + fp16 weights (6Mi)
  char* ws = (char*)d_ws;
  _Float16* x16  = (_Float16*)ws;
  _Float16* wa16 = (_Float16*)(ws + 67108864);
  _Float16* wk16 = (_Float16*)(ws + 67108864 + 2097152);
  _Float16* wv16 = (_Float16*)(ws + 67108864 + 2 * 2097152);
  float4* cP  = (float4*)ws;                // x16 dead after gate_gemm
  float4* cS  = cP + (size_t)CCH * BD4;     // +4 MiB
  float4* hst = cS + (size_t)CCH * BD4;     // +4 MiB

  const int nx8 = M_DIM * D_DIM / 8;
  const int nw8 = D_DIM * D_DIM / 8;
  cvt_f32_f16<<<dim3((nx8 + 255) / 256), dim3(256), 0, stream>>>(x, x16, nx8);
  cvt_f32_f16<<<dim3((nw8 + 255) / 256), dim3(256), 0, stream>>>(Wa, wa16, nw8);
  cvt_f32_f16<<<dim3((nw8 + 255) / 256), dim3(256), 0, stream>>>(Wk, wk16, nw8);
  cvt_f32_f16<<<dim3((nw8 + 255) / 256), dim3(256), 0, stream>>>(Wv, wv16, nw8);

  gate_gemm<<<dim3(M_DIM / 128, D_DIM / 128), dim3(512), 0, stream>>>(
      x16, wa16, wk16, wv16, ba, bk, bv, Aret, Bwr);

  scan_phase1<<<dim3(CCH * BD4 / 256), dim3(256), 0, stream>>>(
      (const float4*)Aret, (const float4*)Bwr, cP, cS);
  scan_phase2<<<dim3(BD4 / 64), dim3(64), 0, stream>>>(
      (const float4*)h0, cP, cS, hst, (float4*)hout);
  scan_phase3<<<dim3(CCH * BD4 / 256), dim3(256), 0, stream>>>(
      hst, (float4*)Aret, (float4*)Bwr);
}

// Round 7
// 700.795 us; speedup vs baseline: 3.7262x; 1.0910x over previous
//
#include <hip/hip_runtime.h>
#include <cstdint>

#define T_DIM 2048
#define B_DIM 16
#define D_DIM 1024
#define M_DIM (T_DIM * B_DIM)        // 32768 rows
#define BD (B_DIM * D_DIM)           // 16384 independent scan states
#define BD4 (BD / 4)                 // 4096 quad-columns
#define CCH 64                       // scan chunks
#define LCH (T_DIM / CCH)            // 32 steps per chunk

typedef _Float16 f16x8 __attribute__((ext_vector_type(8)));
typedef _Float16 f16x2 __attribute__((ext_vector_type(2)));
typedef float f32x4 __attribute__((ext_vector_type(4)));

// async global -> LDS, 16B per lane. LDS dest must be wave-uniform base +
// lane*16. Dest is LINEAR; the bank-conflict swizzle is applied on the
// SOURCE address + the LDS READ (same XOR involution — guide rule #21).
__device__ __forceinline__ void async_cp16(const void* g, void* l) {
  __builtin_amdgcn_global_load_lds(
      (const __attribute__((address_space(1))) void*)(uintptr_t)g,
      (__attribute__((address_space(3))) void*)(uint32_t)(uintptr_t)l,
      16, 0, 0);
}

__device__ __forceinline__ float sigmoidf_(float z) {
  return 1.f / (1.f + __expf(-z));
}
__device__ __forceinline__ float tanhf_(float z) {
  float t = __expf(2.f * z);
  return (t - 1.f) / (t + 1.f);
}

// (a,b) pair packed as two f16 in one u32: lo = a (retain), hi = b (write)
__device__ __forceinline__ uint32_t pack2(float a, float b) {
  f16x2 h; h[0] = (_Float16)a; h[1] = (_Float16)b;
  uint32_t u; __builtin_memcpy(&u, &h, 4); return u;
}
__device__ __forceinline__ float2 unpack2(uint32_t u) {
  f16x2 h; __builtin_memcpy(&h, &u, 4);
  return make_float2((float)h[0], (float)h[1]);
}

// ---------------- f32 -> f16 convert, 8 elems/thread ----------------
__global__ void cvt_f32_f16(const float* __restrict__ s, _Float16* __restrict__ d, int n8) {
  int i = blockIdx.x * blockDim.x + threadIdx.x;
  if (i >= n8) return;
  const float4* sp = (const float4*)s;
  float4 u = sp[2 * i];
  float4 v = sp[2 * i + 1];
  f16x8 o;
  o[0] = (_Float16)u.x; o[1] = (_Float16)u.y; o[2] = (_Float16)u.z; o[3] = (_Float16)u.w;
  o[4] = (_Float16)v.x; o[5] = (_Float16)v.y; o[6] = (_Float16)v.z; o[7] = (_Float16)v.w;
  *(f16x8*)(d + (size_t)i * 8) = o;
}

// ---------------- fused 3-gate GEMM + gate combine ----------------
// Tile 128x128, BK=32, 8 waves (2x4), wave tile 64x32, mfma 16x16x32 f16.
// LDS: 3 buffers x 32 KB, depth-2 prefetch, counted vmcnt (never 0 in loop).
// Swizzle: chunk' = chunk ^ ((row>>1)&3) (verified: conflicts 2.1e7 -> 2.1e6).
// Output: ONE packed u32 array AB[m][e] = (f16 a, f16 b) — halves write bytes.
// 1-D grid, XCD-aware: n-tile = lin&7 -> each XCD keeps its 768KB weight slice
// L2-resident. Epilogue fully unrolled (rule #20).
__global__ __launch_bounds__(512, 2) void gate_gemm(
    const _Float16* __restrict__ x16,
    const _Float16* __restrict__ wa16,
    const _Float16* __restrict__ wk16,
    const _Float16* __restrict__ wv16,
    const float* __restrict__ ba, const float* __restrict__ bk, const float* __restrict__ bv,
    uint32_t* __restrict__ AB) {
  __shared__ __align__(16) char smem[98304];
  // buf b at smem + b*32768: A[128][32] f16 (8 KB) then B[3][128][32] (24 KB)

  const int tid  = threadIdx.x;
  const int wid  = tid >> 6;
  const int lane = tid & 63;
  const int wm = wid >> 2;    // 0..1 : 64-row slab
  const int wn = wid & 3;     // 0..3 : 32-col slab
  const int lr = lane & 15;
  const int kg = lane >> 4;

  const int lin = blockIdx.x;                 // 2048 blocks
  const int m0 = (lin >> 3) * 128;            // 256 m-tiles
  const int n0 = (lin & 7) * 128;             // 8 n-tiles == 8 XCDs

  const int arow = tid >> 2;                      // 0..127
  const int achk = tid & 3;                       // LDS slot this lane fills
  const int aswz = achk ^ ((arow >> 1) & 3);      // global chunk that belongs there

  f32x4 acc[3][4][2];
#pragma unroll
  for (int w = 0; w < 3; ++w)
#pragma unroll
    for (int mi = 0; mi < 4; ++mi)
#pragma unroll
      for (int ni = 0; ni < 2; ++ni)
        acc[w][mi][ni] = (f32x4)0.f;

  const size_t gA0 = (size_t)(m0 + arow) * D_DIM + aswz * 8;
  const size_t gB0 = (size_t)(n0 + arow) * D_DIM + aswz * 8;

  auto stage = [&](int buf, int kk) {
    char* base = smem + buf * 32768;
    async_cp16(x16  + gA0 + kk * 32, base         + tid * 16);
    async_cp16(wa16 + gB0 + kk * 32, base +  8192 + tid * 16);
    async_cp16(wk16 + gB0 + kk * 32, base + 16384 + tid * 16);
    async_cp16(wv16 + gB0 + kk * 32, base + 24576 + tid * 16);
  };

  const int slot = (kg ^ ((lr >> 1) & 3)) * 8;    // swizzled 16B slot (8 f16)

  auto compute = [&](int buf) {
    const _Float16* bufA = (const _Float16*)(smem + buf * 32768);
    const _Float16* bufB = bufA + 4096;           // +8 KB
    f16x8 af[4];
#pragma unroll
    for (int mi = 0; mi < 4; ++mi)
      af[mi] = *(const f16x8*)&bufA[(wm * 64 + mi * 16 + lr) * 32 + slot];
#pragma unroll
    for (int w = 0; w < 3; ++w) {
      f16x8 b0 = *(const f16x8*)&bufB[(w * 128 + wn * 32 + lr) * 32 + slot];
      f16x8 b1 = *(const f16x8*)&bufB[(w * 128 + wn * 32 + 16 + lr) * 32 + slot];
#pragma unroll
      for (int mi = 0; mi < 4; ++mi) {
        acc[w][mi][0] = __builtin_amdgcn_mfma_f32_16x16x32_f16(af[mi], b0, acc[w][mi][0], 0, 0, 0);
        acc[w][mi][1] = __builtin_amdgcn_mfma_f32_16x16x32_f16(af[mi], b1, acc[w][mi][1], 0, 0, 0);
      }
    }
  };

#define STEP(CB, SB, KNEXT)                                   \
  stage(SB, KNEXT);                                           \
  asm volatile("s_waitcnt vmcnt(8)" ::: "memory");            \
  __builtin_amdgcn_s_barrier();                               \
  __builtin_amdgcn_s_setprio(1);                              \
  compute(CB);                                                \
  __builtin_amdgcn_s_setprio(0);                              \
  asm volatile("s_waitcnt lgkmcnt(0)" ::: "memory");          \
  __builtin_amdgcn_s_barrier();                               \
  __builtin_amdgcn_sched_barrier(0);

  // ---- pipelined K-loop: depth-2 prefetch, compile-time buffer indices ----
  stage(0, 0);
  stage(1, 1);
#pragma unroll 1
  for (int kk = 0; kk < 30; kk += 3) {
    STEP(0, 2, kk + 2)
    STEP(1, 0, kk + 3)
    STEP(2, 1, kk + 4)
  }
  // kk = 30 (buf0; outstanding = tiles 30,31)
  asm volatile("s_waitcnt vmcnt(4)" ::: "memory");
  __builtin_amdgcn_s_barrier();
  compute(0);
  asm volatile("s_waitcnt lgkmcnt(0)" ::: "memory");
  __builtin_amdgcn_s_barrier();
  // kk = 31 (buf1)
  asm volatile("s_waitcnt vmcnt(0)" ::: "memory");
  __builtin_amdgcn_s_barrier();
  compute(1);
  asm volatile("s_waitcnt lgkmcnt(0)" ::: "memory");
  __builtin_amdgcn_s_barrier();
  __builtin_amdgcn_sched_barrier(0);
#undef STEP

  // ---- epilogue: gates + combine + pack, LDS-transposed 128B-line stores ----
  // acc C/D mapping (m89): col = lane&15 (=lr), row = kg*4 + r (+mi*16).
  // Per wave: PRIVATE 32x33 u32 buffer (4224B); 8 waves = 33 KiB from smem[0].
  // All waves are past the final barrier; tb is wave-private -> __syncthreads
  // only orders each wave's own LDS writes/reads (cheap, proven correct).
  uint32_t* tbu = (uint32_t*)smem + wid * (32 * 33);
  const float ba_[2] = { ba[n0 + wn * 32 + lr], ba[n0 + wn * 32 + 16 + lr] };
  const float bk_[2] = { bk[n0 + wn * 32 + lr], bk[n0 + wn * 32 + 16 + lr] };
  const float bv_[2] = { bv[n0 + wn * 32 + lr], bv[n0 + wn * 32 + 16 + lr] };

#pragma unroll
  for (int half = 0; half < 2; ++half) {
#pragma unroll
    for (int ni = 0; ni < 2; ++ni)
#pragma unroll
      for (int m2 = 0; m2 < 2; ++m2) {
        const int mi = half * 2 + m2;
#pragma unroll
        for (int r = 0; r < 4; ++r) {
          float sa = sigmoidf_(acc[0][mi][ni][r] + ba_[ni]);
          float sk = sigmoidf_(acc[1][mi][ni][r] + bk_[ni]);
          float tv = tanhf_(acc[2][mi][ni][r] + bv_[ni]);
          tbu[(m2 * 16 + kg * 4 + r) * 33 + ni * 16 + lr] =
              pack2(sa * (1.f - sk), sk * tv);
        }
      }
    __syncthreads();
#pragma unroll
    for (int i = 0; i < 4; ++i) {
      const int rl = i * 8 + (lane >> 3);            // 0..31
      const int cc = (lane & 7) * 4;                 // 0..28
      uint4 v;
      v.x = tbu[rl * 33 + cc + 0];
      v.y = tbu[rl * 33 + cc + 1];
      v.z = tbu[rl * 33 + cc + 2];
      v.w = tbu[rl * 33 + cc + 3];
      const size_t m = (size_t)(m0 + wm * 64 + half * 32 + rl);
      *(uint4*)&AB[m * D_DIM + n0 + wn * 32 + cc] = v;
    }
    __syncthreads();
  }
}

// ---------------- scan phase 1: per-chunk affine composition ----------------
__global__ void scan_phase1(const uint4* __restrict__ AB,
                            float4* __restrict__ cP, float4* __restrict__ cS) {
  int tid = blockIdx.x * 256 + threadIdx.x;       // c*BD4 + bd4
  int bd4 = tid & (BD4 - 1);
  int c   = tid >> 12;
  size_t base = (size_t)c * LCH * BD4 + bd4;
  float4 P = make_float4(1.f, 1.f, 1.f, 1.f);
  float4 S = make_float4(0.f, 0.f, 0.f, 0.f);
#pragma unroll 4
  for (int t = 0; t < LCH; ++t) {
    uint4 u = AB[base + (size_t)t * BD4];
    float2 e0 = unpack2(u.x), e1 = unpack2(u.y), e2 = unpack2(u.z), e3 = unpack2(u.w);
    S.x = fmaf(e0.x, S.x, e0.y); P.x *= e0.x;
    S.y = fmaf(e1.x, S.y, e1.y); P.y *= e1.x;
    S.z = fmaf(e2.x, S.z, e2.y); P.z *= e2.x;
    S.w = fmaf(e3.x, S.w, e3.y); P.w *= e3.x;
  }
  cP[tid] = P;
  cS[tid] = S;
}

// ---------------- scan phase 2: scan 64 chunk summaries per state ----------------
__global__ void scan_phase2(const float4* __restrict__ h0q,
                            const float4* __restrict__ cP, const float4* __restrict__ cS,
                            float4* __restrict__ hst, float4* __restrict__ houtq) {
  int bd4 = blockIdx.x * 64 + threadIdx.x;        // 0..BD4-1
  float4 h = h0q[bd4];
  houtq[bd4] = h;                                  // h[0] = h0
#pragma unroll 4
  for (int c = 0; c < CCH; ++c) {
    hst[(size_t)c * BD4 + bd4] = h;
    float4 p = cP[(size_t)c * BD4 + bd4], s = cS[(size_t)c * BD4 + bd4];
    h.x = fmaf(p.x, h.x, s.x); h.y = fmaf(p.y, h.y, s.y);
    h.z = fmaf(p.z, h.z, s.z); h.w = fmaf(p.w, h.w, s.w);
  }
}

// ---------------- scan phase 3: replay chunks, write h and output ----------------
// ABq aliases the hout[1:] region (packed u32 pairs); each thread reads its
// uint4 then overwrites the same 16B with float4 h — same-thread in-place.
// outq = out region (poison until written here).
__global__ void scan_phase3(const float4* __restrict__ hst,
                            float4* __restrict__ outq, uint4* ABq) {
  int tid = blockIdx.x * 256 + threadIdx.x;
  int bd4 = tid & (BD4 - 1);
  int c   = tid >> 12;
  size_t base = (size_t)c * LCH * BD4 + bd4;
  float4 h = hst[(size_t)c * BD4 + bd4];
#pragma unroll 4
  for (int t = 0; t < LCH; ++t) {
    size_t off = base + (size_t)t * BD4;
    uint4 u = ABq[off];
    float2 e0 = unpack2(u.x), e1 = unpack2(u.y), e2 = unpack2(u.z), e3 = unpack2(u.w);
    h.x = fmaf(e0.x, h.x, e0.y);
    h.y = fmaf(e1.x, h.y, e1.y);
    h.z = fmaf(e2.x, h.z, e2.y);
    h.w = fmaf(e3.x, h.w, e3.y);
    *(float4*)&ABq[off] = h;                       // h[(c*LCH+t)+1]
    float4 o;
    o.x = h.x * h.x * sigmoidf_(h.x);
    o.y = h.y * h.y * sigmoidf_(h.y);
    o.z = h.z * h.z * sigmoidf_(h.z);
    o.w = h.w * h.w * sigmoidf_(h.w);
    outq[off] = o;                                 // hs^2 * sigmoid(hs)
  }
}

extern "C" void kernel_launch(void* const* d_in, const int* in_sizes, int n_in,
                              void* d_out, int out_size, void* d_ws, size_t ws_size,
                              hipStream_t stream) {
  const float* x  = (const float*)d_in[0];
  const float* h0 = (const float*)d_in[1];
  const float* Wa = (const float*)d_in[2];
  const float* ba = (const float*)d_in[3];
  const float* Wk = (const float*)d_in[4];
  const float* bk = (const float*)d_in[5];
  const float* Wv = (const float*)d_in[6];
  const float* bv = (const float*)d_in[7];

  float* out  = (float*)d_out;                       // [T,B,D]
  float* hout = out + (size_t)M_DIM * D_DIM;         // [T+1,B,D]

  // Packed (a,b) f16x2 intermediate aliases hout[1:] (overwritten in place
  // with h by scan_phase3). Same element count, same linear index.
  uint32_t* AB = (uint32_t*)(hout + BD);

  // workspace (~70 MiB): x16 (64Mi, reused by cP/cS/hst) + fp16 weights (6Mi)
  char* ws = (char*)d_ws;
  _Float16* x16  = (_Float16*)ws;
  _Float16* wa16 = (_Float16*)(ws + 67108864);
  _Float16* wk16 = (_Float16*)(ws + 67108864 + 2097152);
  _Float16* wv16 = (_Float16*)(ws + 67108864 + 2 * 2097152);
  float4* cP  = (float4*)ws;                // x16 dead after gate_gemm
  float4* cS  = cP + (size_t)CCH * BD4;     // +4 MiB
  float4* hst = cS + (size_t)CCH * BD4;     // +4 MiB

  const int nx8 = M_DIM * D_DIM / 8;
  const int nw8 = D_DIM * D_DIM / 8;
  cvt_f32_f16<<<dim3((nx8 + 255) / 256), dim3(256), 0, stream>>>(x, x16, nx8);
  cvt_f32_f16<<<dim3((nw8 + 255) / 256), dim3(256), 0, stream>>>(Wa, wa16, nw8);
  cvt_f32_f16<<<dim3((nw8 + 255) / 256), dim3(256), 0, stream>>>(Wk, wk16, nw8);
  cvt_f32_f16<<<dim3((nw8 + 255) / 256), dim3(256), 0, stream>>>(Wv, wv16, nw8);

  gate_gemm<<<dim3(2048), dim3(512), 0, stream>>>(
      x16, wa16, wk16, wv16, ba, bk, bv, AB);

  scan_phase1<<<dim3(CCH * BD4 / 256), dim3(256), 0, stream>>>(
      (const uint4*)AB, cP, cS);
  scan_phase2<<<dim3(BD4 / 64), dim3(64), 0, stream>>>(
      (const float4*)h0, cP, cS, hst, (float4*)hout);
  scan_phase3<<<dim3(CCH * BD4 / 256), dim3(256), 0, stream>>>(
      hst, (float4*)out, (uint4*)AB);
}